// Round 7
// baseline (20274.237 us; speedup 1.0000x reference)
//
#include <hip/hip_runtime.h>
#include <math.h>

#define CIN   16
#define DDEP  8      // conv depth (routing "D")
#define HIN   96
#define WIN   96
#define HOUT  94
#define WOUT  94
#define HW    (HOUT*WOUT)        // 8836
#define CH    256                 // out channels = c*8+d
#define DCAP  8
#define KTOT  (CIN*9)             // 144
#define KTILES 5                  // K padded to 160
#define APAD  168                 // A row stride (bf16 elems)
#define EPSQ  1e-8f

#define B_ELEMS ((size_t)8*DDEP*DCAP*HW)          // 4,524,032 floats
#define WFRAG_ELEMS ((size_t)KTILES*16*64*8)      // 40,960 per half

typedef __attribute__((ext_vector_type(8))) short bf16x8;
typedef __attribute__((ext_vector_type(4))) float f32x4;

// explicit RNE float->bf16 bit conversion
__device__ __forceinline__ ushort f2bf(float f) {
    unsigned u = __float_as_uint(f);
    return (ushort)((u + 0x7FFFu + ((u >> 16) & 1u)) >> 16);
}
__device__ __forceinline__ float bf2f(ushort h) {
    return __uint_as_float(((unsigned)h) << 16);
}

// ---------------------------------------------------------------------------
// W -> MFMA B-fragment order, hi/lo split. frag[kt][nt][lane][j] = W[k][n],
// k = kt*32 + (lane>>4)*8 + j (0 for k>=144), n = nt*16 + (lane&15).
// ---------------------------------------------------------------------------
__global__ __launch_bounds__(64) void build_wfrag(
    const float* __restrict__ w, ushort* __restrict__ w_hi, ushort* __restrict__ w_lo)
{
    const int lane = threadIdx.x;
    const int nt = blockIdx.x, kt = blockIdx.y;
    const int n  = nt*16 + (lane & 15);
    const int kb = kt*32 + (lane >> 4)*8;
    size_t off = (((size_t)kt*16 + nt)*64 + lane)*8;
    for (int j = 0; j < 8; ++j) {
        int k = kb + j;
        float v = (k < KTOT) ? w[(size_t)n*KTOT + k] : 0.f;
        ushort hi = f2bf(v);
        float  r  = v - bf2f(hi);
        ushort lo = f2bf(r);
        w_hi[off + j] = hi; w_lo[off + j] = lo;
    }
}

// ---------------------------------------------------------------------------
// Z[B,D] = sum over (d,h,w) of exp(b). 64 blocks, one per (B,D).
// ---------------------------------------------------------------------------
__global__ __launch_bounds__(256) void softmax_z(
    const float* __restrict__ bws, float* __restrict__ Z)
{
    const int bd = blockIdx.x;
    const float* p = bws + (size_t)bd * (DCAP * HW);
    float sum = 0.f;
    for (int i = threadIdx.x; i < DCAP * HW; i += 256) sum += expf(p[i]);
    #pragma unroll
    for (int off = 1; off < 64; off <<= 1) sum += __shfl_xor(sum, off);
    __shared__ float ps[4];
    if ((threadIdx.x & 63) == 0) ps[threadIdx.x >> 6] = sum;
    __syncthreads();
    if (threadIdx.x == 0) Z[bd] = ps[0] + ps[1] + ps[2] + ps[3];
}

// ---------------------------------------------------------------------------
// Implicit-GEMM MFMA conv + fused routing, IN-REGISTER epilogue (no u_tile).
// MODE 0: iter1 (uniform c), writes b.  MODE 1: iter2, b += db.  MODE 2: write s.
// acc[mt][nt][r]: mt = q*2+mt2; site-in-q: D = mt2*4+quad, spat = r;
// ch = wv*64 + nt*16 + m16; d = m16&7.
// Diagnostics (MODE 2): exhaustive fp32 check of every acc entry -> 777;
// b-sanity (|exp(b)-1|>1e-3) -> 778. Flags merged into t0's own output cells.
// ---------------------------------------------------------------------------
template<int MODE>
__global__ __launch_bounds__(256, 2) void conv_mfma_route(
    const float* __restrict__ x,
    const ushort* __restrict__ w_hi, const ushort* __restrict__ w_lo,
    const float* __restrict__ wfull,
    float* __restrict__ bws, const float* __restrict__ Z,
    float* __restrict__ out)
{
    const int t  = threadIdx.x;
    const int wx = blockIdx.x, hy = blockIdx.y, bp = blockIdx.z;
    const int h0 = hy*2, w0 = wx*2;

    __shared__ float  patch[2][CIN][DDEP][4][4];   // 16384 B
    __shared__ ushort a_hi[64][APAD];              // 21504 B
    __shared__ float  cms[2][64][4];               // 2048 B
    __shared__ float  n2s[4][8][4];                // [wv][d][r]
    __shared__ float  dbs[4][8][8][4];             // [wv][D][d][r]
    __shared__ float  invZ[2][8];
    __shared__ float  sout[256][4];                // 4096 B (MODE 2)
    __shared__ int    flagU, flagB;

    // ---- phase 0 ----
    if (t == 0) { flagU = 0; flagB = 0; }
    if (MODE != 0) {
        if (t < 16) invZ[t>>3][t&7] = 1.0f / Z[(bp*2 + (t>>3))*8 + (t&7)];
        if (t < 128) {
            int q = t >> 6, dd = t & 63;
            #pragma unroll
            for (int s = 0; s < 4; ++s) {
                int sy = s >> 1, sx = s & 1;
                float e = expf(
                    bws[((size_t)(bp*2+q)*64 + dd)*HW + (size_t)(h0+sy)*WOUT + (w0+sx)]);
                cms[q][dd][s] = e;
                if (MODE == 2 && fabsf(e - 1.0f) > 1e-3f) flagB = 1;
            }
        }
    }
    #pragma unroll
    for (int k = 0; k < 16; ++k) {
        int i = t + 256*k;
        int q = i >> 11, r1 = i & 2047;
        int ci = r1 >> 7, rem = r1 & 127;
        int D = rem >> 4, y = (rem >> 2) & 3, xx = rem & 3;
        patch[q][ci][D][y][xx] =
            x[(((size_t)((bp*2+q)*CIN + ci)*DDEP + D)*HIN + (h0+y))*WIN + (w0+xx)];
    }
    __syncthreads();

    // ---- phase 1: im2col -> bf16 A (scalar stores) ----
    {
        const int site = t & 63, quarter = t >> 6;
        const int q = site >> 5, D = (site >> 2) & 7, sy = (site >> 1) & 1, sx = site & 1;
        #pragma unroll
        for (int v = 0; v < 36; ++v) {
            int ci = quarter*4 + v/9;
            int r  = v - (v/9)*9;
            int kh = r/3, kw = r - kh*3;
            a_hi[site][quarter*36 + v] = f2bf(patch[q][ci][D][sy+kh][sx+kw]);
        }
        if (t < 64) {
            #pragma unroll
            for (int kk = KTOT; kk < KTILES*32; ++kk) a_hi[t][kk] = 0;
        }
    }
    __syncthreads();

    // ---- phase 2: MFMA K-loop ----
    const int wv = t >> 6, lane = t & 63;
    const int m16 = lane & 15, quad = lane >> 4;
    f32x4 acc[4][4];
    #pragma unroll
    for (int mt = 0; mt < 4; ++mt)
        #pragma unroll
        for (int nt = 0; nt < 4; ++nt)
            acc[mt][nt] = (f32x4){0.f, 0.f, 0.f, 0.f};

    #pragma unroll
    for (int kt = 0; kt < KTILES; ++kt) {
        bf16x8 ah[4];
        #pragma unroll
        for (int mt = 0; mt < 4; ++mt)
            ah[mt] = *(const bf16x8*)&a_hi[mt*16 + m16][kt*32 + quad*8];
        #pragma unroll
        for (int nt = 0; nt < 4; ++nt) {
            size_t off = (((size_t)kt*16 + (wv*4 + nt))*64 + lane)*8;
            bf16x8 bh = *(const bf16x8*)&w_hi[off];
            bf16x8 bl = *(const bf16x8*)&w_lo[off];
            #pragma unroll
            for (int mt = 0; mt < 4; ++mt) {
                acc[mt][nt] = __builtin_amdgcn_mfma_f32_16x16x32_bf16(ah[mt], bh, acc[mt][nt], 0, 0, 0);
                acc[mt][nt] = __builtin_amdgcn_mfma_f32_16x16x32_bf16(ah[mt], bl, acc[mt][nt], 0, 0, 0);
            }
        }
    }

    // ---- phase 2.5: EXHAUSTIVE probe (MODE 2): every acc entry vs fp32 ----
    if (MODE == 2) {
        bool bad = false;
        for (int mt = 0; mt < 4; ++mt) {
            int pq = mt >> 1, mt2 = mt & 1;
            int pD = mt2*4 + quad;
            for (int r = 0; r < 4; ++r) {
                int psy = r >> 1, psx = r & 1;
                float refv[4] = {0.f, 0.f, 0.f, 0.f};
                for (int k = 0; k < KTOT; ++k) {
                    int ci = k/9, rr = k - ci*9, kh = rr/3, kw = rr - kh*3;
                    float pv = patch[pq][ci][pD][psy+kh][psx+kw];
                    #pragma unroll
                    for (int nt = 0; nt < 4; ++nt)
                        refv[nt] += pv * wfull[(size_t)(wv*64 + nt*16 + m16)*KTOT + k];
                }
                #pragma unroll
                for (int nt = 0; nt < 4; ++nt)
                    if (fabsf(refv[nt] - acc[mt][nt][r]) > 0.02f) bad = true;
            }
        }
        if (bad) flagU = 1;   // benign multi-writer, same value
    }

    // ---- phase 3: in-register epilogue per batch-half q ----
    const int d = m16 & 7;
    for (int q = 0; q < 2; ++q) {
        __syncthreads();   // protects n2s/dbs/sout reuse across q; publishes flags

        // sv[nt][r] = sum_D cm(D,d,r) * u[D][ch] via reg-sum over mt2 + shfl over quad
        float svv[4][4];
        {
            float cmw[2][4];
            if (MODE == 0) {
                const float inv = 1.0f / (float)(DCAP * HW);
                #pragma unroll
                for (int mt2 = 0; mt2 < 2; ++mt2)
                    #pragma unroll
                    for (int r = 0; r < 4; ++r) cmw[mt2][r] = inv;
            } else {
                #pragma unroll
                for (int mt2 = 0; mt2 < 2; ++mt2) {
                    int D = mt2*4 + quad;
                    float iz = invZ[q][D];
                    #pragma unroll
                    for (int r = 0; r < 4; ++r) cmw[mt2][r] = cms[q][D*8 + d][r] * iz;
                }
            }
            #pragma unroll
            for (int nt = 0; nt < 4; ++nt)
                #pragma unroll
                for (int r = 0; r < 4; ++r) {
                    float partial = cmw[0][r]*acc[q*2+0][nt][r] + cmw[1][r]*acc[q*2+1][nt][r];
                    partial += __shfl_xor(partial, 16);
                    partial += __shfl_xor(partial, 32);
                    svv[nt][r] = partial;   // quad-uniform
                }
        }

        if (MODE == 2) {
            if (quad == 0) {
                #pragma unroll
                for (int nt = 0; nt < 4; ++nt) {
                    int ch = wv*64 + nt*16 + m16;
                    #pragma unroll
                    for (int r = 0; r < 4; ++r) sout[ch][r] = svv[nt][r];
                }
            }
            __syncthreads();
            const int bb = bp*2 + q;
            for (int i = t; i < 512; i += 256) {
                int c2 = i >> 1, sy = i & 1;
                float2 v2;
                v2.x = sout[c2][sy*2 + 0];
                v2.y = sout[c2][sy*2 + 1];
                if (q == 0 && i == 0) {          // t0 owns cells (h0,w0),(h0,w0+1)
                    if (flagU) v2.x = 777.0f;
                    if (flagB) v2.y = 778.0f;
                }
                *(float2*)&out[((size_t)bb*CH + c2)*HW + (size_t)(h0+sy)*WOUT + w0] = v2;
            }
            continue;
        }

        // n2(d,r) = sum_c sv^2 : reg-sum over nt + shfl8 + cross-wave LDS
        float p2[4];
        #pragma unroll
        for (int r = 0; r < 4; ++r) {
            float s2 = 0.f;
            #pragma unroll
            for (int nt = 0; nt < 4; ++nt) s2 += svv[nt][r]*svv[nt][r];
            p2[r] = s2;
        }
        #pragma unroll
        for (int r = 0; r < 4; ++r) p2[r] += __shfl_xor(p2[r], 8);
        if (quad == 0 && m16 < 8) {
            #pragma unroll
            for (int r = 0; r < 4; ++r) n2s[wv][m16][r] = p2[r];
        }
        __syncthreads();
        float fac[4];
        #pragma unroll
        for (int r = 0; r < 4; ++r) {
            float n2 = n2s[0][d][r] + n2s[1][d][r] + n2s[2][d][r] + n2s[3][d][r];
            fac[r] = (n2 / (1.f + n2)) / sqrtf(n2 + EPSQ);
        }
        // db(D,d,r) = sum_c u * v
        float qv[2][4];
        #pragma unroll
        for (int mt2 = 0; mt2 < 2; ++mt2)
            #pragma unroll
            for (int r = 0; r < 4; ++r) {
                float sum = 0.f;
                #pragma unroll
                for (int nt = 0; nt < 4; ++nt)
                    sum += acc[q*2+mt2][nt][r] * (svv[nt][r] * fac[r]);
                qv[mt2][r] = sum;
            }
        #pragma unroll
        for (int mt2 = 0; mt2 < 2; ++mt2)
            #pragma unroll
            for (int r = 0; r < 4; ++r) qv[mt2][r] += __shfl_xor(qv[mt2][r], 8);
        if (m16 < 8) {
            #pragma unroll
            for (int mt2 = 0; mt2 < 2; ++mt2) {
                int D = mt2*4 + quad;
                #pragma unroll
                for (int r = 0; r < 4; ++r) dbs[wv][D][m16][r] = qv[mt2][r];
            }
        }
        __syncthreads();
        if (t < 128) {
            const int bb = bp*2 + q;
            int D = t >> 4, d2 = (t >> 1) & 7, sy = t & 1;
            float2 add;
            add.x = dbs[0][D][d2][sy*2+0] + dbs[1][D][d2][sy*2+0]
                  + dbs[2][D][d2][sy*2+0] + dbs[3][D][d2][sy*2+0];
            add.y = dbs[0][D][d2][sy*2+1] + dbs[1][D][d2][sy*2+1]
                  + dbs[2][D][d2][sy*2+1] + dbs[3][D][d2][sy*2+1];
            float2* bpnt = (float2*)&bws[((size_t)(bb*DDEP + D)*DCAP + d2)*HW
                                         + (size_t)(h0+sy)*WOUT + w0];
            if (MODE == 0) {
                *bpnt = add;
            } else {
                float2 old = *bpnt;
                old.x += add.x; old.y += add.y;
                *bpnt = old;
            }
        }
    }
}

// ---------------------------------------------------------------------------
extern "C" void kernel_launch(void* const* d_in, const int* in_sizes, int n_in,
                              void* d_out, int out_size, void* d_ws, size_t ws_size,
                              hipStream_t stream)
{
    (void)in_sizes; (void)n_in; (void)out_size; (void)ws_size;
    const float* x     = (const float*)d_in[0];
    const float* wconv = (const float*)d_in[1];
    float* out = (float*)d_out;

    float*  bws  = (float*)d_ws;
    float*  Z    = bws + B_ELEMS;
    ushort* w_hi = (ushort*)(Z + 64);
    ushort* w_lo = w_hi + WFRAG_ELEMS;

    build_wfrag<<<dim3(16, KTILES), 64, 0, stream>>>(wconv, w_hi, w_lo);
    conv_mfma_route<0><<<dim3(47,47,4), 256, 0, stream>>>(x, w_hi, w_lo, wconv, bws, Z, out);
    softmax_z<<<64, 256, 0, stream>>>(bws, Z);
    conv_mfma_route<1><<<dim3(47,47,4), 256, 0, stream>>>(x, w_hi, w_lo, wconv, bws, Z, out);
    softmax_z<<<64, 256, 0, stream>>>(bws, Z);
    conv_mfma_route<2><<<dim3(47,47,4), 256, 0, stream>>>(x, w_hi, w_lo, wconv, bws, Z, out);
}

// Round 8
// 842.482 us; speedup vs baseline: 24.0649x; 24.0649x over previous
//
#include <hip/hip_runtime.h>
#include <math.h>

#define CIN   16
#define DDEP  8      // conv depth (routing "D")
#define HIN   96
#define WIN   96
#define HOUT  94
#define WOUT  94
#define HW    (HOUT*WOUT)        // 8836
#define CH    256                 // out channels = c*8+d
#define DCAP  8
#define KTOT  (CIN*9)             // 144
#define KTILES 5                  // K padded to 160
#define APAD  168                 // A row stride (bf16 elems)
#define EPSQ  1e-8f

#define B_ELEMS ((size_t)8*DDEP*DCAP*HW)          // 4,524,032 floats
#define WFRAG_ELEMS ((size_t)KTILES*16*64*8)      // 40,960 per half

typedef __attribute__((ext_vector_type(8))) short bf16x8;
typedef __attribute__((ext_vector_type(4))) float f32x4;

// explicit RNE float->bf16 bit conversion
__device__ __forceinline__ ushort f2bf(float f) {
    unsigned u = __float_as_uint(f);
    return (ushort)((u + 0x7FFFu + ((u >> 16) & 1u)) >> 16);
}
__device__ __forceinline__ float bf2f(ushort h) {
    return __uint_as_float(((unsigned)h) << 16);
}

// ---------------------------------------------------------------------------
// W -> MFMA B-fragment order, hi/lo split. frag[kt][nt][lane][j] = W[k][n],
// k = kt*32 + (lane>>4)*8 + j (0 for k>=144), n = nt*16 + (lane&15).
// ---------------------------------------------------------------------------
__global__ __launch_bounds__(64) void build_wfrag(
    const float* __restrict__ w, ushort* __restrict__ w_hi, ushort* __restrict__ w_lo)
{
    const int lane = threadIdx.x;
    const int nt = blockIdx.x, kt = blockIdx.y;
    const int n  = nt*16 + (lane & 15);
    const int kb = kt*32 + (lane >> 4)*8;
    size_t off = (((size_t)kt*16 + nt)*64 + lane)*8;
    for (int j = 0; j < 8; ++j) {
        int k = kb + j;
        float v = (k < KTOT) ? w[(size_t)n*KTOT + k] : 0.f;
        ushort hi = f2bf(v);
        float  r  = v - bf2f(hi);
        ushort lo = f2bf(r);
        w_hi[off + j] = hi; w_lo[off + j] = lo;
    }
}

// ---------------------------------------------------------------------------
// Z[B,D] = sum over (d,h,w) of exp(b). 64 blocks, one per (B,D).
// ---------------------------------------------------------------------------
__global__ __launch_bounds__(256) void softmax_z(
    const float* __restrict__ bws, float* __restrict__ Z)
{
    const int bd = blockIdx.x;
    const float* p = bws + (size_t)bd * (DCAP * HW);
    float sum = 0.f;
    for (int i = threadIdx.x; i < DCAP * HW; i += 256) sum += expf(p[i]);
    #pragma unroll
    for (int off = 1; off < 64; off <<= 1) sum += __shfl_xor(sum, off);
    __shared__ float ps[4];
    if ((threadIdx.x & 63) == 0) ps[threadIdx.x >> 6] = sum;
    __syncthreads();
    if (threadIdx.x == 0) Z[bd] = ps[0] + ps[1] + ps[2] + ps[3];
}

// ---------------------------------------------------------------------------
// Implicit-GEMM MFMA conv + fused routing, IN-REGISTER epilogue.
// MODE 0: iter1 (uniform c), writes b.  MODE 1: iter2, b += db.  MODE 2: write s.
// Block: (wx,hy,bp) -> 2 batches (bp*2+q) x 8 D x 2x2 spatial; M=64, N=256.
// acc[mt][nt][r]: mt = q*2+mt2; D = mt2*4+quad, spat = r;
// ch = wv*64 + nt*16 + m16; d = m16&7.
// NOTE (r7): this structure verified element-exact vs fp32 recompute (probe
// round). Do NOT reintroduce an LDS u_tile round-trip — that path produced
// codegen-sensitive corruption in rounds 4-6.
// ---------------------------------------------------------------------------
template<int MODE>
__global__ __launch_bounds__(256, 2) void conv_mfma_route(
    const float* __restrict__ x,
    const ushort* __restrict__ w_hi, const ushort* __restrict__ w_lo,
    float* __restrict__ bws, const float* __restrict__ Z,
    float* __restrict__ out)
{
    const int t  = threadIdx.x;
    const int wx = blockIdx.x, hy = blockIdx.y, bp = blockIdx.z;
    const int h0 = hy*2, w0 = wx*2;

    __shared__ float  patch[2][CIN][DDEP][4][4];   // 16384 B
    __shared__ ushort a_hi[64][APAD];              // 21504 B
    __shared__ float  cms[2][64][4];               // 2048 B
    __shared__ float  n2s[4][8][4];                // [wv][d][r]
    __shared__ float  dbs[4][8][8][4];             // [wv][D][d][r]
    __shared__ float  invZ[2][8];
    __shared__ float  sout[256][4];                // 4096 B (MODE 2)

    // ---- phase 0: stage b-coeffs + x patch ----
    if (MODE != 0) {
        if (t < 16) invZ[t>>3][t&7] = 1.0f / Z[(bp*2 + (t>>3))*8 + (t&7)];
        if (t < 128) {
            int q = t >> 6, dd = t & 63;
            #pragma unroll
            for (int s = 0; s < 4; ++s) {
                int sy = s >> 1, sx = s & 1;
                cms[q][dd][s] = expf(
                    bws[((size_t)(bp*2+q)*64 + dd)*HW + (size_t)(h0+sy)*WOUT + (w0+sx)]);
            }
        }
    }
    #pragma unroll
    for (int k = 0; k < 16; ++k) {
        int i = t + 256*k;
        int q = i >> 11, r1 = i & 2047;
        int ci = r1 >> 7, rem = r1 & 127;
        int D = rem >> 4, y = (rem >> 2) & 3, xx = rem & 3;
        patch[q][ci][D][y][xx] =
            x[(((size_t)((bp*2+q)*CIN + ci)*DDEP + D)*HIN + (h0+y))*WIN + (w0+xx)];
    }
    __syncthreads();

    // ---- phase 1: im2col -> bf16 A (scalar stores) ----
    {
        const int site = t & 63, quarter = t >> 6;
        const int q = site >> 5, D = (site >> 2) & 7, sy = (site >> 1) & 1, sx = site & 1;
        #pragma unroll
        for (int v = 0; v < 36; ++v) {
            int ci = quarter*4 + v/9;
            int r  = v - (v/9)*9;
            int kh = r/3, kw = r - kh*3;
            a_hi[site][quarter*36 + v] = f2bf(patch[q][ci][D][sy+kh][sx+kw]);
        }
        if (t < 64) {
            #pragma unroll
            for (int kk = KTOT; kk < KTILES*32; ++kk) a_hi[t][kk] = 0;
        }
    }
    __syncthreads();

    // ---- phase 2: MFMA K-loop ----
    const int wv = t >> 6, lane = t & 63;
    const int m16 = lane & 15, quad = lane >> 4;
    f32x4 acc[4][4];
    #pragma unroll
    for (int mt = 0; mt < 4; ++mt)
        #pragma unroll
        for (int nt = 0; nt < 4; ++nt)
            acc[mt][nt] = (f32x4){0.f, 0.f, 0.f, 0.f};

    #pragma unroll
    for (int kt = 0; kt < KTILES; ++kt) {
        bf16x8 ah[4];
        #pragma unroll
        for (int mt = 0; mt < 4; ++mt)
            ah[mt] = *(const bf16x8*)&a_hi[mt*16 + m16][kt*32 + quad*8];
        #pragma unroll
        for (int nt = 0; nt < 4; ++nt) {
            size_t off = (((size_t)kt*16 + (wv*4 + nt))*64 + lane)*8;
            bf16x8 bh = *(const bf16x8*)&w_hi[off];
            bf16x8 bl = *(const bf16x8*)&w_lo[off];
            #pragma unroll
            for (int mt = 0; mt < 4; ++mt) {
                acc[mt][nt] = __builtin_amdgcn_mfma_f32_16x16x32_bf16(ah[mt], bh, acc[mt][nt], 0, 0, 0);
                acc[mt][nt] = __builtin_amdgcn_mfma_f32_16x16x32_bf16(ah[mt], bl, acc[mt][nt], 0, 0, 0);
            }
        }
    }

    // ---- phase 3: in-register epilogue per batch-half q ----
    const int d = m16 & 7;
    for (int q = 0; q < 2; ++q) {
        __syncthreads();   // protects n2s/dbs/sout reuse across q

        // sv[nt][r] = sum_D cm(D,d,r)*u[D][ch] : reg-sum over mt2 + shfl over quad
        float svv[4][4];
        {
            float cmw[2][4];
            if (MODE == 0) {
                const float inv = 1.0f / (float)(DCAP * HW);
                #pragma unroll
                for (int mt2 = 0; mt2 < 2; ++mt2)
                    #pragma unroll
                    for (int r = 0; r < 4; ++r) cmw[mt2][r] = inv;
            } else {
                #pragma unroll
                for (int mt2 = 0; mt2 < 2; ++mt2) {
                    int D = mt2*4 + quad;
                    float iz = invZ[q][D];
                    #pragma unroll
                    for (int r = 0; r < 4; ++r) cmw[mt2][r] = cms[q][D*8 + d][r] * iz;
                }
            }
            #pragma unroll
            for (int nt = 0; nt < 4; ++nt)
                #pragma unroll
                for (int r = 0; r < 4; ++r) {
                    float partial = cmw[0][r]*acc[q*2+0][nt][r] + cmw[1][r]*acc[q*2+1][nt][r];
                    partial += __shfl_xor(partial, 16);
                    partial += __shfl_xor(partial, 32);
                    svv[nt][r] = partial;   // quad-uniform
                }
        }

        if (MODE == 2) {
            if (quad == 0) {
                #pragma unroll
                for (int nt = 0; nt < 4; ++nt) {
                    int ch = wv*64 + nt*16 + m16;
                    #pragma unroll
                    for (int r = 0; r < 4; ++r) sout[ch][r] = svv[nt][r];
                }
            }
            __syncthreads();
            const int bb = bp*2 + q;
            for (int i = t; i < 512; i += 256) {
                int c2 = i >> 1, sy = i & 1;
                float2 v2;
                v2.x = sout[c2][sy*2 + 0];
                v2.y = sout[c2][sy*2 + 1];
                *(float2*)&out[((size_t)bb*CH + c2)*HW + (size_t)(h0+sy)*WOUT + w0] = v2;
            }
            continue;
        }

        // n2(d,r) = sum_c sv^2 : reg-sum over nt + shfl8 + cross-wave LDS
        float p2[4];
        #pragma unroll
        for (int r = 0; r < 4; ++r) {
            float s2 = 0.f;
            #pragma unroll
            for (int nt = 0; nt < 4; ++nt) s2 += svv[nt][r]*svv[nt][r];
            p2[r] = s2;
        }
        #pragma unroll
        for (int r = 0; r < 4; ++r) p2[r] += __shfl_xor(p2[r], 8);
        if (quad == 0 && m16 < 8) {
            #pragma unroll
            for (int r = 0; r < 4; ++r) n2s[wv][m16][r] = p2[r];
        }
        __syncthreads();
        float fac[4];
        #pragma unroll
        for (int r = 0; r < 4; ++r) {
            float n2 = n2s[0][d][r] + n2s[1][d][r] + n2s[2][d][r] + n2s[3][d][r];
            fac[r] = (n2 / (1.f + n2)) / sqrtf(n2 + EPSQ);
        }
        // db(D,d,r) = sum_c u * v
        float qv[2][4];
        #pragma unroll
        for (int mt2 = 0; mt2 < 2; ++mt2)
            #pragma unroll
            for (int r = 0; r < 4; ++r) {
                float sum = 0.f;
                #pragma unroll
                for (int nt = 0; nt < 4; ++nt)
                    sum += acc[q*2+mt2][nt][r] * (svv[nt][r] * fac[r]);
                qv[mt2][r] = sum;
            }
        #pragma unroll
        for (int mt2 = 0; mt2 < 2; ++mt2)
            #pragma unroll
            for (int r = 0; r < 4; ++r) qv[mt2][r] += __shfl_xor(qv[mt2][r], 8);
        if (m16 < 8) {
            #pragma unroll
            for (int mt2 = 0; mt2 < 2; ++mt2) {
                int D = mt2*4 + quad;
                #pragma unroll
                for (int r = 0; r < 4; ++r) dbs[wv][D][m16][r] = qv[mt2][r];
            }
        }
        __syncthreads();
        if (t < 128) {
            const int bb = bp*2 + q;
            int D = t >> 4, d2 = (t >> 1) & 7, sy = t & 1;
            float2 add;
            add.x = dbs[0][D][d2][sy*2+0] + dbs[1][D][d2][sy*2+0]
                  + dbs[2][D][d2][sy*2+0] + dbs[3][D][d2][sy*2+0];
            add.y = dbs[0][D][d2][sy*2+1] + dbs[1][D][d2][sy*2+1]
                  + dbs[2][D][d2][sy*2+1] + dbs[3][D][d2][sy*2+1];
            float2* bpnt = (float2*)&bws[((size_t)(bb*DDEP + D)*DCAP + d2)*HW
                                         + (size_t)(h0+sy)*WOUT + w0];
            if (MODE == 0) {
                *bpnt = add;
            } else {
                float2 old = *bpnt;
                old.x += add.x; old.y += add.y;
                *bpnt = old;
            }
        }
    }
}

// ---------------------------------------------------------------------------
extern "C" void kernel_launch(void* const* d_in, const int* in_sizes, int n_in,
                              void* d_out, int out_size, void* d_ws, size_t ws_size,
                              hipStream_t stream)
{
    (void)in_sizes; (void)n_in; (void)out_size; (void)ws_size;
    const float* x     = (const float*)d_in[0];
    const float* wconv = (const float*)d_in[1];
    float* out = (float*)d_out;

    float*  bws  = (float*)d_ws;
    float*  Z    = bws + B_ELEMS;
    ushort* w_hi = (ushort*)(Z + 64);
    ushort* w_lo = w_hi + WFRAG_ELEMS;

    build_wfrag<<<dim3(16, KTILES), 64, 0, stream>>>(wconv, w_hi, w_lo);
    conv_mfma_route<0><<<dim3(47,47,4), 256, 0, stream>>>(x, w_hi, w_lo, bws, Z, out);
    softmax_z<<<64, 256, 0, stream>>>(bws, Z);
    conv_mfma_route<1><<<dim3(47,47,4), 256, 0, stream>>>(x, w_hi, w_lo, bws, Z, out);
    softmax_z<<<64, 256, 0, stream>>>(bws, Z);
    conv_mfma_route<2><<<dim3(47,47,4), 256, 0, stream>>>(x, w_hi, w_lo, bws, Z, out);
}

// Round 9
// 827.741 us; speedup vs baseline: 24.4934x; 1.0178x over previous
//
#include <hip/hip_runtime.h>
#include <math.h>

#define CIN   16
#define DDEP  8      // conv depth (routing "D")
#define HIN   96
#define WIN   96
#define HOUT  94
#define WOUT  94
#define HW    (HOUT*WOUT)        // 8836
#define CH    256                 // out channels = c*8+d
#define DCAP  8
#define KTOT  (CIN*9)             // 144
#define KTILES 5                  // K padded to 160
#define APAD  168                 // A row stride (bf16 elems)
#define EPSQ  1e-8f

#define B_ELEMS ((size_t)8*DDEP*DCAP*HW)          // 4,524,032 floats
#define WFRAG_ELEMS ((size_t)KTILES*16*64*8)      // 40,960 per half

typedef __attribute__((ext_vector_type(8))) short bf16x8;
typedef __attribute__((ext_vector_type(4))) float f32x4;

// explicit RNE float->bf16 bit conversion
__device__ __forceinline__ ushort f2bf(float f) {
    unsigned u = __float_as_uint(f);
    return (ushort)((u + 0x7FFFu + ((u >> 16) & 1u)) >> 16);
}
__device__ __forceinline__ float bf2f(ushort h) {
    return __uint_as_float(((unsigned)h) << 16);
}

// ---------------------------------------------------------------------------
// W -> MFMA B-fragment order, hi/lo split. frag[kt][nt][lane][j] = W[k][n],
// k = kt*32 + (lane>>4)*8 + j (0 for k>=144), n = nt*16 + (lane&15).
// ---------------------------------------------------------------------------
__global__ __launch_bounds__(64) void build_wfrag(
    const float* __restrict__ w, ushort* __restrict__ w_hi, ushort* __restrict__ w_lo)
{
    const int lane = threadIdx.x;
    const int nt = blockIdx.x, kt = blockIdx.y;
    const int n  = nt*16 + (lane & 15);
    const int kb = kt*32 + (lane >> 4)*8;
    size_t off = (((size_t)kt*16 + nt)*64 + lane)*8;
    for (int j = 0; j < 8; ++j) {
        int k = kb + j;
        float v = (k < KTOT) ? w[(size_t)n*KTOT + k] : 0.f;
        ushort hi = f2bf(v);
        float  r  = v - bf2f(hi);
        ushort lo = f2bf(r);
        w_hi[off + j] = hi; w_lo[off + j] = lo;
    }
}

// ---------------------------------------------------------------------------
// Z[B,D] = sum over (d,h,w) of exp(b). 64 blocks, one per (B,D).
// ---------------------------------------------------------------------------
__global__ __launch_bounds__(256) void softmax_z(
    const float* __restrict__ bws, float* __restrict__ Z)
{
    const int bd = blockIdx.x;
    const float* p = bws + (size_t)bd * (DCAP * HW);
    float sum = 0.f;
    for (int i = threadIdx.x; i < DCAP * HW; i += 256) sum += expf(p[i]);
    #pragma unroll
    for (int off = 1; off < 64; off <<= 1) sum += __shfl_xor(sum, off);
    __shared__ float ps[4];
    if ((threadIdx.x & 63) == 0) ps[threadIdx.x >> 6] = sum;
    __syncthreads();
    if (threadIdx.x == 0) Z[bd] = ps[0] + ps[1] + ps[2] + ps[3];
}

// ---------------------------------------------------------------------------
// Implicit-GEMM MFMA conv + fused routing, IN-REGISTER epilogue.
// MODE 0: iter1 (uniform c), writes b.  MODE 1: iter2, b += db.  MODE 2: write s.
// Block: (wx,h0,bb) -> 1 batch x 8 D x 1 h-row x 8 consecutive w; M=64, N=256.
// M-row m = D*8 + wi  (wi = w - w0).  Site w = w0 + wi, valid iff w < 94.
// acc[mt][nt][r]: m = mt*16 + quad*4 + r -> D = mt*2 + (quad>>1),
//                 wi = (quad&1)*4 + r;  ch = wv*64 + nt*16 + m16; d = m16&7.
// NOTE (r7): MFMA + in-register epilogue verified element-exact vs fp32.
// Do NOT reintroduce an LDS u_tile round-trip (rounds 4-6 corruption).
// r9: re-tiled spatial 2x2 -> 1x8 for HBM line efficiency (r8 was BW-bound
// on 4-8x amplified traffic from 8-16B granules).
// ---------------------------------------------------------------------------
template<int MODE>
__global__ __launch_bounds__(256, 2) void conv_mfma_route(
    const float* __restrict__ x,
    const ushort* __restrict__ w_hi, const ushort* __restrict__ w_lo,
    float* __restrict__ bws, const float* __restrict__ Z,
    float* __restrict__ out)
{
    const int t  = threadIdx.x;
    const int wx = blockIdx.x, h0 = blockIdx.y, bb = blockIdx.z;
    const int w0 = wx*8;

    __shared__ float  patch[CIN][DDEP][3][10];   // 15360 B
    __shared__ ushort a_hi[64][APAD];            // 21504 B
    __shared__ float  cms[64][8];                // [D*8+d][wi] 2048 B
    __shared__ float  n2s[4][8][8];              // [wv][d][wi] 1024 B
    __shared__ float  dbs[4][8][8][8];           // [wv][D][d][wi] 8192 B
    __shared__ float  invZ[8];
    __shared__ float  sout[256][8];              // MODE 2 staging 8192 B

    // ---- phase 0: stage c-coeffs + x patch ----
    if (MODE != 0) {
        if (t < 8) invZ[t] = 1.0f / Z[bb*8 + t];
        for (int v = t; v < 512; v += 256) {
            int Dd = v >> 3, wi = v & 7;
            int w = w0 + wi;
            float bv = (w < WOUT) ? bws[((size_t)bb*64 + Dd)*HW + (size_t)h0*WOUT + w] : 0.f;
            cms[Dd][wi] = expf(bv);
        }
    }
    for (int i = t; i < CIN*DDEP*3*10; i += 256) {
        int ci = i / 240, rem = i - ci*240;
        int D  = rem / 30, rem2 = rem - D*30;
        int kh = rem2 / 10, col = rem2 - kh*10;
        int xc = w0 + col; if (xc > 95) xc = 95;   // clamp: garbage feeds only invalid sites
        patch[ci][D][kh][col] =
            x[(((size_t)(bb*CIN + ci)*DDEP + D)*HIN + (h0+kh))*WIN + xc];
    }
    __syncthreads();

    // ---- phase 1: im2col -> bf16 A (uint stores; thread = site x kgroup) ----
    {
        const int site = t >> 2, kg = t & 3;     // site = D*8 + wi
        const int D = site >> 3, wi = site & 7;
        #pragma unroll
        for (int u2 = 0; u2 < 18; ++u2) {
            int k0 = kg*36 + u2*2;
            int ci0 = k0/9, r0 = k0 - ci0*9, kh0 = r0/3, kw0 = r0 - kh0*3;
            int k1 = k0 + 1;
            int ci1 = k1/9, r1 = k1 - ci1*9, kh1 = r1/3, kw1 = r1 - kh1*3;
            unsigned lo = f2bf(patch[ci0][D][kh0][wi+kw0]);
            unsigned hi = f2bf(patch[ci1][D][kh1][wi+kw1]);
            *(unsigned*)&a_hi[site][k0] = lo | (hi << 16);
        }
        if (t < 64) {
            #pragma unroll
            for (int kk = KTOT; kk < KTILES*32; kk += 2)
                *(unsigned*)&a_hi[t][kk] = 0u;
        }
    }
    __syncthreads();

    // ---- phase 2: MFMA K-loop ----
    const int wv = t >> 6, lane = t & 63;
    const int m16 = lane & 15, quad = lane >> 4;
    f32x4 acc[4][4];
    #pragma unroll
    for (int mt = 0; mt < 4; ++mt)
        #pragma unroll
        for (int nt = 0; nt < 4; ++nt)
            acc[mt][nt] = (f32x4){0.f, 0.f, 0.f, 0.f};

    #pragma unroll
    for (int kt = 0; kt < KTILES; ++kt) {
        bf16x8 ah[4];
        #pragma unroll
        for (int mt = 0; mt < 4; ++mt)
            ah[mt] = *(const bf16x8*)&a_hi[mt*16 + m16][kt*32 + quad*8];
        #pragma unroll
        for (int nt = 0; nt < 4; ++nt) {
            size_t off = (((size_t)kt*16 + (wv*4 + nt))*64 + lane)*8;
            bf16x8 bh = *(const bf16x8*)&w_hi[off];
            bf16x8 bl = *(const bf16x8*)&w_lo[off];
            #pragma unroll
            for (int mt = 0; mt < 4; ++mt) {
                acc[mt][nt] = __builtin_amdgcn_mfma_f32_16x16x32_bf16(ah[mt], bh, acc[mt][nt], 0, 0, 0);
                acc[mt][nt] = __builtin_amdgcn_mfma_f32_16x16x32_bf16(ah[mt], bl, acc[mt][nt], 0, 0, 0);
            }
        }
    }

    // ---- phase 3: in-register epilogue ----
    const int d   = m16 & 7;
    const int Dq  = quad >> 1;      // D parity bit (lane bit5)
    const int wih = quad & 1;       // wi half (lane bit4)

    // sv[nt][r] = sum_D cm(D,d,wi)*u(D,...): reg-sum over mt + shfl_xor(32) over Dq
    float svv[4][4];
    {
        float cmw[4][4];
        if (MODE == 0) {
            const float inv = 1.0f / (float)(DCAP * HW);
            #pragma unroll
            for (int mt = 0; mt < 4; ++mt)
                #pragma unroll
                for (int r = 0; r < 4; ++r) cmw[mt][r] = inv;
        } else {
            #pragma unroll
            for (int mt = 0; mt < 4; ++mt) {
                int D = mt*2 + Dq;
                float iz = invZ[D];
                #pragma unroll
                for (int r = 0; r < 4; ++r) cmw[mt][r] = cms[D*8 + d][wih*4 + r] * iz;
            }
        }
        #pragma unroll
        for (int nt = 0; nt < 4; ++nt)
            #pragma unroll
            for (int r = 0; r < 4; ++r) {
                float partial = 0.f;
                #pragma unroll
                for (int mt = 0; mt < 4; ++mt) partial += cmw[mt][r]*acc[mt][nt][r];
                partial += __shfl_xor(partial, 32);
                svv[nt][r] = partial;   // uniform in lane bit5
            }
    }

    if (MODE == 2) {
        if (quad < 2) {   // one Dq copy per (wih, m16, nt)
            #pragma unroll
            for (int nt = 0; nt < 4; ++nt) {
                int ch = wv*64 + nt*16 + m16;
                #pragma unroll
                for (int r = 0; r < 4; ++r) sout[ch][wih*4 + r] = svv[nt][r];
            }
        }
        __syncthreads();
        for (int i = t; i < 1024; i += 256) {
            int c2 = i >> 2, wip = i & 3;
            int w = w0 + wip*2;
            if (w + 1 < WOUT) {
                float2 v2 = { sout[c2][wip*2], sout[c2][wip*2 + 1] };
                *(float2*)&out[((size_t)bb*CH + c2)*HW + (size_t)h0*WOUT + w] = v2;
            }
        }
        return;
    }

    // n2(d,wi) = sum_c sv^2 : reg-sum over nt + shfl_xor(8) + cross-wave LDS
    float p2[4];
    #pragma unroll
    for (int r = 0; r < 4; ++r) {
        float s2 = 0.f;
        #pragma unroll
        for (int nt = 0; nt < 4; ++nt) s2 += svv[nt][r]*svv[nt][r];
        p2[r] = s2;
    }
    #pragma unroll
    for (int r = 0; r < 4; ++r) p2[r] += __shfl_xor(p2[r], 8);
    if (quad < 2 && m16 < 8) {
        #pragma unroll
        for (int r = 0; r < 4; ++r) n2s[wv][m16][quad*4 + r] = p2[r];
    }
    __syncthreads();
    float fac[4];
    #pragma unroll
    for (int r = 0; r < 4; ++r) {
        int wi = wih*4 + r;
        float n2 = n2s[0][d][wi] + n2s[1][d][wi] + n2s[2][d][wi] + n2s[3][d][wi];
        fac[r] = (n2 / (1.f + n2)) / sqrtf(n2 + EPSQ);
    }
    // db(D,d,wi) = sum_c u*v : reg-sum over nt + shfl_xor(8) + cross-wave LDS
    float qv[4][4];
    #pragma unroll
    for (int mt = 0; mt < 4; ++mt)
        #pragma unroll
        for (int r = 0; r < 4; ++r) {
            float sum = 0.f;
            #pragma unroll
            for (int nt = 0; nt < 4; ++nt)
                sum += acc[mt][nt][r] * (svv[nt][r] * fac[r]);
            qv[mt][r] = sum;
        }
    #pragma unroll
    for (int mt = 0; mt < 4; ++mt)
        #pragma unroll
        for (int r = 0; r < 4; ++r) qv[mt][r] += __shfl_xor(qv[mt][r], 8);
    if (m16 < 8) {
        #pragma unroll
        for (int mt = 0; mt < 4; ++mt) {
            int D = mt*2 + Dq;
            #pragma unroll
            for (int r = 0; r < 4; ++r) dbs[wv][D][m16][wih*4 + r] = qv[mt][r];
        }
    }
    __syncthreads();
    // b write: 64 (D,d) x 8 wi, float2 runs (coalesced 32-B granules)
    {
        int Dd = t >> 2, wip = t & 3;
        int D = Dd >> 3, d2 = Dd & 7;
        int w = w0 + wip*2;
        if (w + 1 < WOUT) {
            int wi = wip*2;
            float2 add;
            add.x = dbs[0][D][d2][wi]   + dbs[1][D][d2][wi]
                  + dbs[2][D][d2][wi]   + dbs[3][D][d2][wi];
            add.y = dbs[0][D][d2][wi+1] + dbs[1][D][d2][wi+1]
                  + dbs[2][D][d2][wi+1] + dbs[3][D][d2][wi+1];
            float2* bp = (float2*)&bws[((size_t)bb*64 + Dd)*HW + (size_t)h0*WOUT + w];
            if (MODE == 0) {
                *bp = add;
            } else {
                float2 old = *bp;
                old.x += add.x; old.y += add.y;
                *bp = old;
            }
        }
    }
}

// ---------------------------------------------------------------------------
extern "C" void kernel_launch(void* const* d_in, const int* in_sizes, int n_in,
                              void* d_out, int out_size, void* d_ws, size_t ws_size,
                              hipStream_t stream)
{
    (void)in_sizes; (void)n_in; (void)out_size; (void)ws_size;
    const float* x     = (const float*)d_in[0];
    const float* wconv = (const float*)d_in[1];
    float* out = (float*)d_out;

    float*  bws  = (float*)d_ws;
    float*  Z    = bws + B_ELEMS;
    ushort* w_hi = (ushort*)(Z + 64);
    ushort* w_lo = w_hi + WFRAG_ELEMS;

    build_wfrag<<<dim3(16, KTILES), 64, 0, stream>>>(wconv, w_hi, w_lo);
    conv_mfma_route<0><<<dim3(12,94,8), 256, 0, stream>>>(x, w_hi, w_lo, bws, Z, out);
    softmax_z<<<64, 256, 0, stream>>>(bws, Z);
    conv_mfma_route<1><<<dim3(12,94,8), 256, 0, stream>>>(x, w_hi, w_lo, bws, Z, out);
    softmax_z<<<64, 256, 0, stream>>>(bws, Z);
    conv_mfma_route<2><<<dim3(12,94,8), 256, 0, stream>>>(x, w_hi, w_lo, bws, Z, out);
}